// Round 3
// baseline (447.237 us; speedup 1.0000x reference)
//
#include <hip/hip_runtime.h>
#include <math.h>

#define EMB 64

typedef float f32x4 __attribute__((ext_vector_type(4)));

// Pass 1: offs[g] = lower_bound(member_groups, g) for g in [0, G]; offs[G] = M.
// member_groups sorted ascending. Thread j fills offs for every group whose
// range starts at index j (gap-fill between mg[j-1] and mg[j]).
__global__ __launch_bounds__(256) void boundaries_kernel(
    const int* __restrict__ member_groups,
    int num_members,
    const int* __restrict__ num_groups_p,
    int* __restrict__ offs)
{
    const int j = blockIdx.x * blockDim.x + threadIdx.x;
    if (j >= num_members) return;
    const int gj = member_groups[j];
    if (j == 0) {
        for (int g = 0; g <= gj; ++g) offs[g] = 0;
    } else {
        const int gp = member_groups[j - 1];
        for (int g = gp + 1; g <= gj; ++g) offs[g] = j;
    }
    if (j == num_members - 1) {
        const int G = *num_groups_p;
        for (int g = gj + 1; g <= G; ++g) offs[g] = num_members;
    }
}

// Pass 2: one wave per batch element.
// Lane layout: sub = lane>>4 (member slot 0..3), q = lane&15 (dim quad).
// Each wave-wide float4 load fetches FOUR member rows at once; 4-deep unroll
// puts 16 rows in flight per wave.
__global__ __launch_bounds__(256) void consrec_kernel(
    const float* __restrict__ user_emb,
    const float* __restrict__ item_emb,
    const float* __restrict__ w1,     // [64][8]
    const float* __restrict__ b1,     // [8]
    const float* __restrict__ w2,     // [8]
    const float* __restrict__ b2,     // [1]
    const int*   __restrict__ member_users,
    const int*   __restrict__ offs,   // [G+1]
    const int*   __restrict__ group_inputs,
    const int*   __restrict__ item_inputs,
    int batch,
    float* __restrict__ out)
{
    const int wave = (int)((blockIdx.x * blockDim.x + threadIdx.x) >> 6);
    const int lane = threadIdx.x & 63;
    if (wave >= batch) return;

    const int sub = lane >> 4;   // member slot within 4-row load
    const int q   = lane & 15;   // dim quad (dims 4q..4q+3)

    const int g     = group_inputs[wave];
    const int start = offs[g];
    const int end   = offs[g + 1];
    const int cnt   = end - start;

    f32x4 s4 = {0.f, 0.f, 0.f, 0.f};
    for (int base = start; base < end; base += 64) {
        const int m = min(64, end - base);
        const int uvec = (lane < m) ? member_users[base + lane] : 0;
        int j = 0;
        // main: 16 members per iteration -> 4 independent x4 loads (16 rows)
        for (; j + 16 <= m; j += 16) {
            const int u0 = __shfl(uvec, j + 0  + sub, 64);
            const int u1 = __shfl(uvec, j + 4  + sub, 64);
            const int u2 = __shfl(uvec, j + 8  + sub, 64);
            const int u3 = __shfl(uvec, j + 12 + sub, 64);
            const f32x4 v0 = *(const f32x4*)(user_emb + ((size_t)u0 << 6) + (q << 2));
            const f32x4 v1 = *(const f32x4*)(user_emb + ((size_t)u1 << 6) + (q << 2));
            const f32x4 v2 = *(const f32x4*)(user_emb + ((size_t)u2 << 6) + (q << 2));
            const f32x4 v3 = *(const f32x4*)(user_emb + ((size_t)u3 << 6) + (q << 2));
            s4 += v0; s4 += v1; s4 += v2; s4 += v3;
        }
        // tail: 4 members (masked) per iteration
        for (; j < m; j += 4) {
            const int mi = j + sub;
            const int u  = __shfl(uvec, mi & 63, 64);
            if (mi < m) {
                const f32x4 v = *(const f32x4*)(user_emb + ((size_t)u << 6) + (q << 2));
                s4 += v;
            }
        }
    }

    // reduce across the 4 member slots (lanes q, q+16, q+32, q+48)
    #pragma unroll
    for (int off = 16; off <= 32; off <<= 1) {
        f32x4 t;
        t.x = __shfl_xor(s4.x, off, 64);
        t.y = __shfl_xor(s4.y, off, 64);
        t.z = __shfl_xor(s4.z, off, 64);
        t.w = __shfl_xor(s4.w, off, 64);
        s4 += t;
    }

    const float inv = 1.f / (float)(cnt > 0 ? cnt : 1);
    const f32x4 item4 = *(const f32x4*)(item_emb + ((size_t)item_inputs[wave] << 6) + (q << 2));
    const f32x4 x4 = s4 * inv * item4;

    // h_k = sum_d x_d * w1[d][k]; lane covers dims 4q..4q+3 (dup x4 across subs)
    float p[8];
    #pragma unroll
    for (int k = 0; k < 8; ++k) {
        const int d0 = q << 2;
        p[k] = x4.x * w1[(d0 + 0) * 8 + k]
             + x4.y * w1[(d0 + 1) * 8 + k]
             + x4.z * w1[(d0 + 2) * 8 + k]
             + x4.w * w1[(d0 + 3) * 8 + k];
    }
    // reduce across the 16 dim-quads (higher lane groups are duplicates)
    #pragma unroll
    for (int off = 1; off <= 8; off <<= 1) {
        #pragma unroll
        for (int k = 0; k < 8; ++k) p[k] += __shfl_xor(p[k], off, 64);
    }

    float acc = b2[0];
    #pragma unroll
    for (int k = 0; k < 8; ++k) {
        float h = p[k] + b1[k];
        h = h > 0.f ? h : 0.f;
        acc += h * w2[k];
    }
    const float y = 1.f / (1.f + expf(-acc));
    if (lane == 0) out[wave] = y;
}

extern "C" void kernel_launch(void* const* d_in, const int* in_sizes, int n_in,
                              void* d_out, int out_size, void* d_ws, size_t ws_size,
                              hipStream_t stream) {
    const float* user_emb      = (const float*)d_in[0];
    const float* item_emb      = (const float*)d_in[1];
    const float* w1            = (const float*)d_in[2];
    const float* b1            = (const float*)d_in[3];
    const float* w2            = (const float*)d_in[4];
    const float* b2            = (const float*)d_in[5];
    const int*   member_users  = (const int*)d_in[6];
    const int*   member_groups = (const int*)d_in[7];
    const int*   group_inputs  = (const int*)d_in[8];
    const int*   item_inputs   = (const int*)d_in[9];
    const int*   num_groups_p  = (const int*)d_in[10];

    const int num_members = in_sizes[6];
    const int batch       = in_sizes[8];

    int* offs = (int*)d_ws;   // (G+1) ints ~ 400 KB

    {
        const int threads = 256;
        const int grid = (num_members + threads - 1) / threads;
        boundaries_kernel<<<grid, threads, 0, stream>>>(
            member_groups, num_members, num_groups_p, offs);
    }
    {
        const int threads = 256;                 // 4 waves/block
        const int waves_per_block = threads / 64;
        const int grid = (batch + waves_per_block - 1) / waves_per_block;
        consrec_kernel<<<grid, threads, 0, stream>>>(
            user_emb, item_emb, w1, b1, w2, b2,
            member_users, offs, group_inputs, item_inputs,
            batch, (float*)d_out);
    }
}